// Round 1
// baseline (1748.284 us; speedup 1.0000x reference)
//
#include <hip/hip_runtime.h>

#define S_LEN 2048
#define HID 4096
#define NH 32
#define HD 128

typedef __attribute__((ext_vector_type(8))) short bf16x8;
typedef __attribute__((ext_vector_type(4))) float f32x4;

__device__ __forceinline__ unsigned short f2bf(float f) {
    unsigned int u = __float_as_uint(f);
    u += 0x7FFF + ((u >> 16) & 1);
    return (unsigned short)(u >> 16);
}
__device__ __forceinline__ float bf2f(unsigned short h) {
    return __uint_as_float(((unsigned int)h) << 16);
}

// ---------------- GEMM: C[M,N] = A[M,K] * B[K,N] via bf16 MFMA ----------------
#define BM 128
#define BN 128
#define BK 64
#define LRS 72   // LDS row stride in bf16 elements (144B: 16B-aligned rows, <=2-way banks)

template<bool A_BF16, bool OUT_BF16>
__global__ __launch_bounds__(256)
void gemm_bf16(const void* __restrict__ Ap, const float* __restrict__ B,
               void* __restrict__ Cp, int M, int N, int K)
{
    __shared__ unsigned short As[BM * LRS];
    __shared__ unsigned short Bs[BN * LRS];
    const int tid = threadIdx.x;
    const int l = tid & 63;
    const int l15 = l & 15, lg = l >> 4;
    const int wid = tid >> 6;
    const int wm = (wid >> 1) * 64;
    const int wn = (wid & 1) * 64;
    const int m0 = blockIdx.y * BM;
    const int n0 = blockIdx.x * BN;

    f32x4 acc[4][4] = {};

    const int arow = tid >> 4;        // 0..15
    const int acol = (tid & 15) * 4;  // 0..60
    const int bn = tid & 127;
    const int bk4 = (tid >> 7) * 4;   // 0 or 4

    for (int k0 = 0; k0 < K; k0 += BK) {
        // stage A[128][64] -> LDS bf16 (row-major, k contiguous)
        #pragma unroll
        for (int q = 0; q < 8; ++q) {
            int m = arow + q * 16;
            if (A_BF16) {
                const unsigned short* A = (const unsigned short*)Ap;
                ushort4 v = *(const ushort4*)&A[(size_t)(m0 + m) * K + k0 + acol];
                *(ushort4*)&As[m * LRS + acol] = v;
            } else {
                const float* A = (const float*)Ap;
                float4 v = *(const float4*)&A[(size_t)(m0 + m) * K + k0 + acol];
                ushort4 o; o.x = f2bf(v.x); o.y = f2bf(v.y); o.z = f2bf(v.z); o.w = f2bf(v.w);
                *(ushort4*)&As[m * LRS + acol] = o;
            }
        }
        // stage B[64][128] transposed -> Bs[n][k] (coalesced dword loads per k-row)
        #pragma unroll
        for (int g = 0; g < 8; ++g) {
            int k = g * 8 + bk4;
            ushort4 o;
            o.x = f2bf(B[(size_t)(k0 + k + 0) * N + n0 + bn]);
            o.y = f2bf(B[(size_t)(k0 + k + 1) * N + n0 + bn]);
            o.z = f2bf(B[(size_t)(k0 + k + 2) * N + n0 + bn]);
            o.w = f2bf(B[(size_t)(k0 + k + 3) * N + n0 + bn]);
            *(ushort4*)&Bs[bn * LRS + k] = o;
        }
        __syncthreads();
        #pragma unroll
        for (int kk = 0; kk < 2; ++kk) {
            bf16x8 af[4], bfr[4];
            #pragma unroll
            for (int i = 0; i < 4; ++i)
                af[i] = *(const bf16x8*)&As[(wm + i * 16 + l15) * LRS + kk * 32 + lg * 8];
            #pragma unroll
            for (int j = 0; j < 4; ++j)
                bfr[j] = *(const bf16x8*)&Bs[(wn + j * 16 + l15) * LRS + kk * 32 + lg * 8];
            #pragma unroll
            for (int i = 0; i < 4; ++i)
                #pragma unroll
                for (int j = 0; j < 4; ++j)
                    acc[i][j] = __builtin_amdgcn_mfma_f32_16x16x32_bf16(af[i], bfr[j], acc[i][j], 0, 0, 0);
        }
        __syncthreads();
    }
    // epilogue: C row = (l>>4)*4+reg, col = l&15 (verified gfx950 C/D layout)
    const int cr = lg * 4;
    #pragma unroll
    for (int i = 0; i < 4; ++i) {
        #pragma unroll
        for (int j = 0; j < 4; ++j) {
            #pragma unroll
            for (int r = 0; r < 4; ++r) {
                int row = m0 + wm + i * 16 + cr + r;
                int col = n0 + wn + j * 16 + l15;
                float v = acc[i][j][r];
                if (OUT_BF16) ((unsigned short*)Cp)[(size_t)row * N + col] = f2bf(v);
                else          ((float*)Cp)[(size_t)row * N + col] = v;
            }
        }
    }
}

// ---------------- per-head LayerNorm + RoPE, in place on bf16 [S*NH][HD] ----------------
__global__ __launch_bounds__(256)
void ln_rope(unsigned short* __restrict__ X,
             const float* __restrict__ gamma, const float* __restrict__ beta,
             const int* __restrict__ pos)
{
    const int tid = threadIdx.x;
    const int l = tid & 63;
    const int w = tid >> 6;
    const int row = blockIdx.x * 4 + w;   // row = s*NH + h
    const int s = row >> 5;               // NH = 32
    unsigned short* p = X + (size_t)row * HD;

    float lo = bf2f(p[l]);
    float hi = bf2f(p[l + 64]);
    float sum = lo + hi;
    #pragma unroll
    for (int off = 32; off >= 1; off >>= 1) sum += __shfl_xor(sum, off, 64);
    float mu = sum * (1.0f / 128.0f);
    float dlo = lo - mu, dhi = hi - mu;
    float vs = dlo * dlo + dhi * dhi;
    #pragma unroll
    for (int off = 32; off >= 1; off >>= 1) vs += __shfl_xor(vs, off, 64);
    float rstd = rsqrtf(vs * (1.0f / 128.0f) + 1e-5f);
    float xlo = dlo * rstd * gamma[l] + beta[l];
    float xhi = dhi * rstd * gamma[l + 64] + beta[l + 64];

    // RoPE: lane l holds (d=l, d=l+64) which is exactly the rotate-half pair; same freq.
    float fpos = (float)pos[s];
    float invf = exp2f(-13.287712379549449f * (float)l * (1.0f / 64.0f)); // 10000^(-l/64)
    float ang = fpos * invf;
    float sn, cs;
    sincosf(ang, &sn, &cs);
    p[l]      = f2bf(xlo * cs - xhi * sn);
    p[l + 64] = f2bf(xhi * cs + xlo * sn);
}

// ---------------- causal flash attention, bf16 MFMA ----------------
#define KBLK 32
#define VRS 40

__global__ __launch_bounds__(256)
void attn_fwd(const unsigned short* __restrict__ Q,
              const unsigned short* __restrict__ Kb,
              const unsigned short* __restrict__ Vb,
              unsigned short* __restrict__ O)
{
    __shared__ unsigned short Ks[KBLK * HD];   // XOR-swizzled rows (256B rows)
    __shared__ unsigned short Vt[HD * VRS];    // V transposed [d][kv], pad 40
    __shared__ unsigned short Ps[4][16 * VRS]; // per-wave P tile

    const int tid = threadIdx.x;
    const int l = tid & 63;
    const int w = tid >> 6;
    const int l15 = l & 15, lg = l >> 4;
    const int h = blockIdx.y;
    const int q0 = blockIdx.x * 64;
    const int qw = q0 + w * 16;

    // Q fragments (A operand): row = l&15, k = (l>>4)*8 contiguous
    bf16x8 qf[4];
    #pragma unroll
    for (int d = 0; d < 4; ++d)
        qf[d] = *(const bf16x8*)&Q[(size_t)(qw + l15) * HID + h * HD + d * 32 + lg * 8];

    f32x4 o_acc[8] = {};
    float mrow[4], lrow[4];
    #pragma unroll
    for (int r = 0; r < 4; ++r) { mrow[r] = -1e30f; lrow[r] = 0.0f; }

    const float scale = 0.08838834764831845f; // 128^-0.5

    const int nt = (q0 + 64) / KBLK;
    for (int t = 0; t < nt; ++t) {
        const int kv0 = t * KBLK;
        {   // stage K tile (32 rows x 128), swizzled: byte ^= (row&7)<<4
            int row = tid >> 3;
            int cb = (tid & 7) * 32;
            const char* src = (const char*)&Kb[(size_t)(kv0 + row) * HID + h * HD];
            char* dst = (char*)Ks + row * 256;
            int sw = (row & 7) << 4;
            *(bf16x8*)(dst + ((cb) ^ sw))      = *(const bf16x8*)(src + cb);
            *(bf16x8*)(dst + ((cb + 16) ^ sw)) = *(const bf16x8*)(src + cb + 16);
        }
        {   // stage V transposed: Vt[d][kv]
            int d = tid & 127;
            int kvb = (tid >> 7) * 4;
            #pragma unroll
            for (int g = 0; g < 4; ++g) {
                int kv = g * 8 + kvb;
                ushort4 o4;
                o4.x = Vb[(size_t)(kv0 + kv + 0) * HID + h * HD + d];
                o4.y = Vb[(size_t)(kv0 + kv + 1) * HID + h * HD + d];
                o4.z = Vb[(size_t)(kv0 + kv + 2) * HID + h * HD + d];
                o4.w = Vb[(size_t)(kv0 + kv + 3) * HID + h * HD + d];
                *(ushort4*)&Vt[d * VRS + kv] = o4;
            }
        }
        __syncthreads();

        // S = Q K^T  (B operand: col=kv=l&15 -> K row, k=d contiguous)
        f32x4 sc[2] = {};
        #pragma unroll
        for (int kvf = 0; kvf < 2; ++kvf) {
            int r = kvf * 16 + l15;
            int sw = (r & 7) << 4;
            #pragma unroll
            for (int d = 0; d < 4; ++d) {
                int cb = (d * 32 + lg * 8) * 2;
                bf16x8 kf = *(const bf16x8*)((const char*)Ks + r * 256 + (cb ^ sw));
                sc[kvf] = __builtin_amdgcn_mfma_f32_16x16x32_bf16(qf[d], kf, sc[kvf], 0, 0, 0);
            }
        }

        // online softmax; C layout: q_local=(l>>4)*4+r, kv_local=l&15
        #pragma unroll
        for (int r = 0; r < 4; ++r) {
            int qg = qw + lg * 4 + r;
            float s0 = (kv0 + l15      <= qg) ? sc[0][r] * scale : -1e30f;
            float s1 = (kv0 + 16 + l15 <= qg) ? sc[1][r] * scale : -1e30f;
            float mx = fmaxf(s0, s1);
            #pragma unroll
            for (int off = 8; off >= 1; off >>= 1) mx = fmaxf(mx, __shfl_xor(mx, off, 64));
            float mn = fmaxf(mrow[r], mx);
            float corr = __expf(mrow[r] - mn);
            float p0 = __expf(s0 - mn);
            float p1 = __expf(s1 - mn);
            float rs = p0 + p1;
            #pragma unroll
            for (int off = 8; off >= 1; off >>= 1) rs += __shfl_xor(rs, off, 64);
            lrow[r] = lrow[r] * corr + rs;
            mrow[r] = mn;
            #pragma unroll
            for (int df = 0; df < 8; ++df) o_acc[df][r] *= corr;
            int ql = lg * 4 + r;
            Ps[w][ql * VRS + l15]      = f2bf(p0);
            Ps[w][ql * VRS + 16 + l15] = f2bf(p1);
        }

        // O += P V   (A: row=q=l&15, k=kv contiguous; B: col=d=l&15 -> Vt row)
        bf16x8 pa = *(const bf16x8*)&Ps[w][l15 * VRS + lg * 8];
        #pragma unroll
        for (int df = 0; df < 8; ++df) {
            bf16x8 vf = *(const bf16x8*)&Vt[(df * 16 + l15) * VRS + lg * 8];
            o_acc[df] = __builtin_amdgcn_mfma_f32_16x16x32_bf16(pa, vf, o_acc[df], 0, 0, 0);
        }
        __syncthreads();
    }

    #pragma unroll
    for (int df = 0; df < 8; ++df) {
        #pragma unroll
        for (int r = 0; r < 4; ++r) {
            int q = qw + lg * 4 + r;
            int d = h * HD + df * 16 + l15;
            O[(size_t)q * HID + d] = f2bf(o_acc[df][r] / lrow[r]);
        }
    }
}

extern "C" void kernel_launch(void* const* d_in, const int* in_sizes, int n_in,
                              void* d_out, int out_size, void* d_ws, size_t ws_size,
                              hipStream_t stream)
{
    (void)in_sizes; (void)n_in; (void)out_size; (void)ws_size;
    const float* X    = (const float*)d_in[0];
    const int*   pos  = (const int*)d_in[1];
    const float* Wq   = (const float*)d_in[2];
    const float* Wk   = (const float*)d_in[3];
    const float* Wv   = (const float*)d_in[4];
    const float* Wo   = (const float*)d_in[5];
    const float* qn_w = (const float*)d_in[6];
    const float* qn_b = (const float*)d_in[7];
    const float* kn_w = (const float*)d_in[8];
    const float* kn_b = (const float*)d_in[9];
    float* out = (float*)d_out;

    unsigned short* Qb = (unsigned short*)d_ws;
    unsigned short* Kb = Qb + (size_t)S_LEN * HID;
    unsigned short* Vb = Kb + (size_t)S_LEN * HID;
    unsigned short* Ab = Vb + (size_t)S_LEN * HID;

    dim3 blk(256);
    dim3 ggrid(HID / BN, S_LEN / BM);

    gemm_bf16<false, true><<<ggrid, blk, 0, stream>>>(X, Wq, Qb, S_LEN, HID, HID);
    gemm_bf16<false, true><<<ggrid, blk, 0, stream>>>(X, Wk, Kb, S_LEN, HID, HID);
    gemm_bf16<false, true><<<ggrid, blk, 0, stream>>>(X, Wv, Vb, S_LEN, HID, HID);

    ln_rope<<<dim3(S_LEN * NH / 4), blk, 0, stream>>>(Qb, qn_w, qn_b, pos);
    ln_rope<<<dim3(S_LEN * NH / 4), blk, 0, stream>>>(Kb, kn_w, kn_b, pos);

    attn_fwd<<<dim3(S_LEN / 64, NH), blk, 0, stream>>>(Qb, Kb, Vb, Ab);

    gemm_bf16<true, false><<<ggrid, blk, 0, stream>>>(Ab, Wo, out, S_LEN, HID, HID);
}

// Round 2
// 742.226 us; speedup vs baseline: 2.3555x; 2.3555x over previous
//
#include <hip/hip_runtime.h>

#define S_LEN 2048
#define HID 4096
#define NH 32
#define HD 128
#define QKV_N 12288   // 3*HID

typedef __attribute__((ext_vector_type(8))) short bf16x8;
typedef __attribute__((ext_vector_type(4))) float f32x4;

__device__ __forceinline__ unsigned short f2bf(float f) {
    unsigned int u = __float_as_uint(f);
    u += 0x7FFF + ((u >> 16) & 1);
    return (unsigned short)(u >> 16);
}
__device__ __forceinline__ float bf2f(unsigned short h) {
    return __uint_as_float(((unsigned int)h) << 16);
}

typedef __attribute__((address_space(1))) const void gconst_void;
typedef __attribute__((address_space(3))) void lds_void;
__device__ __forceinline__ void gl16(const void* g, void* l) {
    __builtin_amdgcn_global_load_lds((gconst_void*)g, (lds_void*)l, 16, 0, 0);
}

// ---------------- fp32 -> bf16 linear convert ----------------
__global__ __launch_bounds__(256)
void cvt_f32_bf16(const float* __restrict__ in, unsigned short* __restrict__ out, int n8)
{
    int i = blockIdx.x * 256 + threadIdx.x;
    if (i >= n8) return;
    const float4* p = (const float4*)in + (size_t)i * 2;
    float4 a = p[0], b = p[1];
    bf16x8 o;
    o[0] = (short)f2bf(a.x); o[1] = (short)f2bf(a.y); o[2] = (short)f2bf(a.z); o[3] = (short)f2bf(a.w);
    o[4] = (short)f2bf(b.x); o[5] = (short)f2bf(b.y); o[6] = (short)f2bf(b.z); o[7] = (short)f2bf(b.w);
    *((bf16x8*)out + i) = o;
}

// ---------------- fp32 [K][N] -> bf16 [N][K] transpose-convert ----------------
__global__ __launch_bounds__(256)
void cvt_w_t(const float* __restrict__ W, unsigned short* __restrict__ Wt, int N, int K)
{
    __shared__ unsigned short t[64][72];
    const int tid = threadIdx.x;
    const int n0 = blockIdx.x * 64, k0 = blockIdx.y * 64;
    const int c4 = (tid & 15) * 4;   // n within tile
    const int r  = tid >> 4;         // k within tile (16 rows/pass)
    #pragma unroll
    for (int p = 0; p < 4; ++p) {
        float4 v = *(const float4*)&W[(size_t)(k0 + r + p * 16) * N + n0 + c4];
        ushort4 o;
        o.x = f2bf(v.x); o.y = f2bf(v.y); o.z = f2bf(v.z); o.w = f2bf(v.w);
        *(ushort4*)&t[r + p * 16][c4] = o;
    }
    __syncthreads();
    const int n = tid >> 2;
    const int kq = (tid & 3) * 16;
    unsigned short* dst = &Wt[(size_t)(n0 + n) * K + k0 + kq];
    bf16x8 v0, v1;
    #pragma unroll
    for (int j = 0; j < 8; ++j) v0[j] = (short)t[kq + j][n];
    #pragma unroll
    for (int j = 0; j < 8; ++j) v1[j] = (short)t[kq + 8 + j][n];
    *(bf16x8*)dst = v0;
    *(bf16x8*)(dst + 8) = v1;
}

// ---------------- GEMM: C[M,N] = A[M,K] * Bt[N,K]^T, bf16 MFMA, gload_lds staging ----------------
template<bool OUT_BF16>
__global__ __launch_bounds__(256)
void gemm_tn(const unsigned short* __restrict__ A,   // [M][K] bf16
             const unsigned short* __restrict__ Bt,  // [N][K] bf16
             void* __restrict__ Cp, int M, int N, int K)
{
    __shared__ unsigned short As[128 * 64];
    __shared__ unsigned short Bs[128 * 64];
    const int tid = threadIdx.x;
    const int l = tid & 63;
    const int l15 = l & 15, lg = l >> 4;
    const int wid = tid >> 6;
    const int wm = (wid >> 1) * 64, wn = (wid & 1) * 64;
    const int m0 = blockIdx.y * 128;
    const int n0 = blockIdx.x * 128;

    const int srow = tid >> 3;           // 0..31
    const int skoff = (tid & 7) * 8;     // k offset in elems (16B chunks)
    const size_t arow0 = (size_t)(m0 + srow) * K + skoff;
    const size_t brow0 = (size_t)(n0 + srow) * K + skoff;

    f32x4 acc[4][4] = {};

    for (int k0 = 0; k0 < K; k0 += 64) {
        #pragma unroll
        for (int q = 0; q < 4; ++q)
            gl16(&A[arow0 + (size_t)q * 32 * K + k0], &As[(q * 32 + srow) * 64 + skoff]);
        #pragma unroll
        for (int q = 0; q < 4; ++q)
            gl16(&Bt[brow0 + (size_t)q * 32 * K + k0], &Bs[(q * 32 + srow) * 64 + skoff]);
        __syncthreads();
        #pragma unroll
        for (int kk = 0; kk < 2; ++kk) {
            bf16x8 af[4], bfr[4];
            #pragma unroll
            for (int i = 0; i < 4; ++i)
                af[i] = *(const bf16x8*)&As[(wm + i * 16 + l15) * 64 + kk * 32 + lg * 8];
            #pragma unroll
            for (int j = 0; j < 4; ++j)
                bfr[j] = *(const bf16x8*)&Bs[(wn + j * 16 + l15) * 64 + kk * 32 + lg * 8];
            #pragma unroll
            for (int i = 0; i < 4; ++i)
                #pragma unroll
                for (int j = 0; j < 4; ++j)
                    acc[i][j] = __builtin_amdgcn_mfma_f32_16x16x32_bf16(af[i], bfr[j], acc[i][j], 0, 0, 0);
        }
        __syncthreads();
    }

    const int cr = lg * 4;
    #pragma unroll
    for (int i = 0; i < 4; ++i) {
        #pragma unroll
        for (int j = 0; j < 4; ++j) {
            #pragma unroll
            for (int r = 0; r < 4; ++r) {
                int row = m0 + wm + i * 16 + cr + r;
                int col = n0 + wn + j * 16 + l15;
                float v = acc[i][j][r];
                if (OUT_BF16) ((unsigned short*)Cp)[(size_t)row * N + col] = f2bf(v);
                else          ((float*)Cp)[(size_t)row * N + col] = v;
            }
        }
    }
}

// ---------------- per-head LayerNorm + RoPE, in place on combined QKV bf16 [S][12288] ----------------
__global__ __launch_bounds__(256)
void ln_rope(unsigned short* __restrict__ QKV,
             const float* __restrict__ qg, const float* __restrict__ qb,
             const float* __restrict__ kg, const float* __restrict__ kb,
             const int* __restrict__ pos)
{
    const int tid = threadIdx.x;
    const int l = tid & 63;
    const int w = tid >> 6;
    const int rid = blockIdx.x * 4 + w;   // rid in [0, S*64): s * 64 + (which*32 + h)
    const int s = rid >> 6;
    const int hh = rid & 63;
    const int which = hh >> 5;            // 0 = Q slab, 1 = K slab
    const int h = hh & 31;
    unsigned short* p = QKV + (size_t)s * QKV_N + which * HID + h * HD;
    const float* gamma = which ? kg : qg;
    const float* beta  = which ? kb : qb;

    float lo = bf2f(p[l]);
    float hi = bf2f(p[l + 64]);
    float sum = lo + hi;
    #pragma unroll
    for (int off = 32; off >= 1; off >>= 1) sum += __shfl_xor(sum, off, 64);
    float mu = sum * (1.0f / 128.0f);
    float dlo = lo - mu, dhi = hi - mu;
    float vs = dlo * dlo + dhi * dhi;
    #pragma unroll
    for (int off = 32; off >= 1; off >>= 1) vs += __shfl_xor(vs, off, 64);
    float rstd = rsqrtf(vs * (1.0f / 128.0f) + 1e-5f);
    float xlo = dlo * rstd * gamma[l] + beta[l];
    float xhi = dhi * rstd * gamma[l + 64] + beta[l + 64];

    float fpos = (float)pos[s];
    float invf = exp2f(-13.287712379549449f * (float)l * (1.0f / 64.0f)); // 10000^(-l/64)
    float ang = fpos * invf;
    float sn, cs;
    sincosf(ang, &sn, &cs);
    p[l]      = f2bf(xlo * cs - xhi * sn);
    p[l + 64] = f2bf(xhi * cs + xlo * sn);
}

// ---------------- causal flash attention, bf16 MFMA ----------------
#define KBLK 32
#define VRS 40

__global__ __launch_bounds__(256)
void attn_fwd(const unsigned short* __restrict__ QKV,   // [S][12288]
              unsigned short* __restrict__ O)           // [S][4096]
{
    __shared__ unsigned short Ks[KBLK * HD];   // XOR-swizzled rows (256B rows)
    __shared__ unsigned short Vt[HD * VRS];    // V transposed [d][kv]
    __shared__ unsigned short Ps[4][16 * VRS];

    const int tid = threadIdx.x;
    const int l = tid & 63;
    const int w = tid >> 6;
    const int l15 = l & 15, lg = l >> 4;
    const int h = blockIdx.y;
    const int q0 = blockIdx.x * 64;
    const int qw = q0 + w * 16;

    const unsigned short* Qp = QKV + h * HD;
    const unsigned short* Kp = QKV + HID + h * HD;
    const unsigned short* Vp = QKV + 2 * HID + h * HD;

    bf16x8 qf[4];
    #pragma unroll
    for (int d = 0; d < 4; ++d)
        qf[d] = *(const bf16x8*)&Qp[(size_t)(qw + l15) * QKV_N + d * 32 + lg * 8];

    f32x4 o_acc[8] = {};
    float mrow[4], lrow[4];
    #pragma unroll
    for (int r = 0; r < 4; ++r) { mrow[r] = -1e30f; lrow[r] = 0.0f; }

    const float scale = 0.08838834764831845f;

    const int nt = (q0 + 64) / KBLK;
    for (int t = 0; t < nt; ++t) {
        const int kv0 = t * KBLK;
        {   // stage K tile (32 x 128), byte ^= (row&7)<<4
            int row = tid >> 3;
            int cb = (tid & 7) * 32;
            const char* src = (const char*)&Kp[(size_t)(kv0 + row) * QKV_N];
            char* dst = (char*)Ks + row * 256;
            int sw = (row & 7) << 4;
            *(bf16x8*)(dst + ((cb) ^ sw))      = *(const bf16x8*)(src + cb);
            *(bf16x8*)(dst + ((cb + 16) ^ sw)) = *(const bf16x8*)(src + cb + 16);
        }
        {   // stage V transposed: Vt[d][kv]
            int d = tid & 127;
            int kvb = (tid >> 7) * 4;
            #pragma unroll
            for (int g = 0; g < 4; ++g) {
                int kv = g * 8 + kvb;
                ushort4 o4;
                o4.x = Vp[(size_t)(kv0 + kv + 0) * QKV_N + d];
                o4.y = Vp[(size_t)(kv0 + kv + 1) * QKV_N + d];
                o4.z = Vp[(size_t)(kv0 + kv + 2) * QKV_N + d];
                o4.w = Vp[(size_t)(kv0 + kv + 3) * QKV_N + d];
                *(ushort4*)&Vt[d * VRS + kv] = o4;
            }
        }
        __syncthreads();

        f32x4 sc[2] = {};
        #pragma unroll
        for (int kvf = 0; kvf < 2; ++kvf) {
            int r = kvf * 16 + l15;
            int sw = (r & 7) << 4;
            #pragma unroll
            for (int d = 0; d < 4; ++d) {
                int cb = (d * 32 + lg * 8) * 2;
                bf16x8 kf = *(const bf16x8*)((const char*)Ks + r * 256 + (cb ^ sw));
                sc[kvf] = __builtin_amdgcn_mfma_f32_16x16x32_bf16(qf[d], kf, sc[kvf], 0, 0, 0);
            }
        }

        #pragma unroll
        for (int r = 0; r < 4; ++r) {
            int qg = qw + lg * 4 + r;
            float s0 = (kv0 + l15      <= qg) ? sc[0][r] * scale : -1e30f;
            float s1 = (kv0 + 16 + l15 <= qg) ? sc[1][r] * scale : -1e30f;
            float mx = fmaxf(s0, s1);
            #pragma unroll
            for (int off = 8; off >= 1; off >>= 1) mx = fmaxf(mx, __shfl_xor(mx, off, 64));
            float mn = fmaxf(mrow[r], mx);
            float corr = __expf(mrow[r] - mn);
            float p0 = __expf(s0 - mn);
            float p1 = __expf(s1 - mn);
            float rs = p0 + p1;
            #pragma unroll
            for (int off = 8; off >= 1; off >>= 1) rs += __shfl_xor(rs, off, 64);
            lrow[r] = lrow[r] * corr + rs;
            mrow[r] = mn;
            #pragma unroll
            for (int df = 0; df < 8; ++df) o_acc[df][r] *= corr;
            int ql = lg * 4 + r;
            Ps[w][ql * VRS + l15]      = f2bf(p0);
            Ps[w][ql * VRS + 16 + l15] = f2bf(p1);
        }

        bf16x8 pa = *(const bf16x8*)&Ps[w][l15 * VRS + lg * 8];
        #pragma unroll
        for (int df = 0; df < 8; ++df) {
            bf16x8 vf = *(const bf16x8*)&Vt[(df * 16 + l15) * VRS + lg * 8];
            o_acc[df] = __builtin_amdgcn_mfma_f32_16x16x32_bf16(pa, vf, o_acc[df], 0, 0, 0);
        }
        __syncthreads();
    }

    #pragma unroll
    for (int df = 0; df < 8; ++df) {
        #pragma unroll
        for (int r = 0; r < 4; ++r) {
            int q = qw + lg * 4 + r;
            int d = h * HD + df * 16 + l15;
            O[(size_t)q * HID + d] = f2bf(o_acc[df][r] / lrow[r]);
        }
    }
}

extern "C" void kernel_launch(void* const* d_in, const int* in_sizes, int n_in,
                              void* d_out, int out_size, void* d_ws, size_t ws_size,
                              hipStream_t stream)
{
    (void)in_sizes; (void)n_in; (void)out_size; (void)ws_size;
    const float* X    = (const float*)d_in[0];
    const int*   pos  = (const int*)d_in[1];
    const float* Wq   = (const float*)d_in[2];
    const float* Wk   = (const float*)d_in[3];
    const float* Wv   = (const float*)d_in[4];
    const float* Wo   = (const float*)d_in[5];
    const float* qn_w = (const float*)d_in[6];
    const float* qn_b = (const float*)d_in[7];
    const float* kn_w = (const float*)d_in[8];
    const float* kn_b = (const float*)d_in[9];
    float* out = (float*)d_out;

    // ws layout (bytes): Xb/Ab @0 (16.8MB) | QKVb @16777216 (50.3MB) | Wt @67108864 (100.7MB)
    unsigned short* Xb    = (unsigned short*)d_ws;                  // also reused as attn output
    unsigned short* QKVb  = (unsigned short*)((char*)d_ws + 16777216);
    unsigned short* Wt    = (unsigned short*)((char*)d_ws + 67108864);
    unsigned short* Ab    = Xb;

    dim3 blk(256);

    // 1) X -> bf16
    cvt_f32_bf16<<<dim3((S_LEN * HID / 8 + 255) / 256), blk, 0, stream>>>(X, Xb, S_LEN * HID / 8);

    // 2) weights -> bf16 transposed [N][K]; Wq/Wk/Wv stacked to [12288][4096]
    dim3 tgrid(HID / 64, HID / 64);
    cvt_w_t<<<tgrid, blk, 0, stream>>>(Wq, Wt,                                  HID, HID);
    cvt_w_t<<<tgrid, blk, 0, stream>>>(Wk, Wt + (size_t)HID * HID,              HID, HID);
    cvt_w_t<<<tgrid, blk, 0, stream>>>(Wv, Wt + (size_t)2 * HID * HID,          HID, HID);

    // 3) fused QKV GEMM: [2048,4096] x [4096,12288] -> QKVb bf16
    gemm_tn<true><<<dim3(QKV_N / 128, S_LEN / 128), blk, 0, stream>>>(Xb, Wt, QKVb, S_LEN, QKV_N, HID);

    // 4) LN + RoPE on Q and K slabs
    ln_rope<<<dim3(S_LEN * 64 / 4), blk, 0, stream>>>(QKVb, qn_w, qn_b, kn_w, kn_b, pos);

    // 5) attention -> Ab (aliases Xb, which is dead now)
    attn_fwd<<<dim3(S_LEN / 64, NH), blk, 0, stream>>>(QKVb, Ab);

    // 6) Wo -> bf16 transposed (reuse Wt space; QKV weights dead)
    cvt_w_t<<<tgrid, blk, 0, stream>>>(Wo, Wt, HID, HID);

    // 7) output projection -> fp32 d_out
    gemm_tn<false><<<dim3(HID / 128, S_LEN / 128), blk, 0, stream>>>(Ab, Wt, out, S_LEN, HID, HID);
}

// Round 3
// 701.025 us; speedup vs baseline: 2.4939x; 1.0588x over previous
//
#include <hip/hip_runtime.h>

#define S_LEN 2048
#define HID 4096
#define NH 32
#define HD 128
#define QKV_N 12288   // 3*HID

typedef __attribute__((ext_vector_type(8))) short bf16x8;
typedef __attribute__((ext_vector_type(4))) float f32x4;

__device__ __forceinline__ unsigned short f2bf(float f) {
    unsigned int u = __float_as_uint(f);
    u += 0x7FFF + ((u >> 16) & 1);
    return (unsigned short)(u >> 16);
}
__device__ __forceinline__ float bf2f(unsigned short h) {
    return __uint_as_float(((unsigned int)h) << 16);
}

typedef __attribute__((address_space(1))) const void gconst_void;
typedef __attribute__((address_space(3))) void lds_void;
__device__ __forceinline__ void gl16(const void* g, void* l) {
    __builtin_amdgcn_global_load_lds((gconst_void*)g, (lds_void*)l, 16, 0, 0);
}

#define VMCNT(n) asm volatile("s_waitcnt vmcnt(" #n ")" ::: "memory")
#define LGKM0()  asm volatile("s_waitcnt lgkmcnt(0)" ::: "memory")
#define BAR()    do { asm volatile("" ::: "memory"); __builtin_amdgcn_s_barrier(); asm volatile("" ::: "memory"); } while (0)

// ---------------- fp32 -> bf16 linear convert ----------------
__global__ __launch_bounds__(256)
void cvt_f32_bf16(const float* __restrict__ in, unsigned short* __restrict__ out, int n8)
{
    int i = blockIdx.x * 256 + threadIdx.x;
    if (i >= n8) return;
    const float4* p = (const float4*)in + (size_t)i * 2;
    float4 a = p[0], b = p[1];
    bf16x8 o;
    o[0] = (short)f2bf(a.x); o[1] = (short)f2bf(a.y); o[2] = (short)f2bf(a.z); o[3] = (short)f2bf(a.w);
    o[4] = (short)f2bf(b.x); o[5] = (short)f2bf(b.y); o[6] = (short)f2bf(b.z); o[7] = (short)f2bf(b.w);
    *((bf16x8*)out + i) = o;
}

// ---------------- fp32 [K][N] -> bf16 [N][K] transpose-convert ----------------
__global__ __launch_bounds__(256)
void cvt_w_t(const float* __restrict__ W, unsigned short* __restrict__ Wt, int N, int K)
{
    __shared__ unsigned short t[64][72];
    const int tid = threadIdx.x;
    const int n0 = blockIdx.x * 64, k0 = blockIdx.y * 64;
    const int c4 = (tid & 15) * 4;
    const int r  = tid >> 4;
    #pragma unroll
    for (int p = 0; p < 4; ++p) {
        float4 v = *(const float4*)&W[(size_t)(k0 + r + p * 16) * N + n0 + c4];
        ushort4 o;
        o.x = f2bf(v.x); o.y = f2bf(v.y); o.z = f2bf(v.z); o.w = f2bf(v.w);
        *(ushort4*)&t[r + p * 16][c4] = o;
    }
    __syncthreads();
    const int n = tid >> 2;
    const int kq = (tid & 3) * 16;
    unsigned short* dst = &Wt[(size_t)(n0 + n) * K + k0 + kq];
    bf16x8 v0, v1;
    #pragma unroll
    for (int j = 0; j < 8; ++j) v0[j] = (short)t[kq + j][n];
    #pragma unroll
    for (int j = 0; j < 8; ++j) v1[j] = (short)t[kq + 8 + j][n];
    *(bf16x8*)dst = v0;
    *(bf16x8*)(dst + 8) = v1;
}

// ---------------- 256x256 8-phase GEMM: C = A[M,K] * Bt[N,K]^T ----------------
__device__ __forceinline__ void lda4(bf16x8 af[4][2], const char* base, int rq, int l15, int lg) {
    const int sw = (l15 & 7) << 4;
    #pragma unroll
    for (int i = 0; i < 4; ++i) {
        const char* rb = base + ((rq * 4 + i) * 16 + l15) * 128;
        af[i][0] = *(const bf16x8*)(rb + ((lg * 16) ^ sw));
        af[i][1] = *(const bf16x8*)(rb + ((64 + lg * 16) ^ sw));
    }
}
__device__ __forceinline__ void ldb2(bf16x8 bf[2][2], const char* base, int cq, int l15, int lg) {
    const int sw = (l15 & 7) << 4;
    #pragma unroll
    for (int j = 0; j < 2; ++j) {
        const char* rb = base + ((cq * 2 + j) * 16 + l15) * 128;
        bf[j][0] = *(const bf16x8*)(rb + ((lg * 16) ^ sw));
        bf[j][1] = *(const bf16x8*)(rb + ((64 + lg * 16) ^ sw));
    }
}
__device__ __forceinline__ void mfma16(f32x4 acc[8][4], const bf16x8 af[4][2], const bf16x8 bf[2][2],
                                       int mi0, int nj0) {
    __builtin_amdgcn_s_setprio(1);
    #pragma unroll
    for (int kk = 0; kk < 2; ++kk)
        #pragma unroll
        for (int i = 0; i < 4; ++i)
            #pragma unroll
            for (int j = 0; j < 2; ++j)
                acc[mi0 + i][nj0 + j] =
                    __builtin_amdgcn_mfma_f32_16x16x32_bf16(af[i][kk], bf[j][kk], acc[mi0 + i][nj0 + j], 0, 0, 0);
    __builtin_amdgcn_s_setprio(0);
}
__device__ __forceinline__ void stage2(const unsigned short* g, char* dst, int K, int r32, int kn) {
    gl16(g + (size_t)r32 * K + kn, dst);
    gl16(g + (size_t)(r32 + 8) * K + kn, dst + 1024);
}

template<bool OUT_BF16>
__global__ __launch_bounds__(512, 2)
void gemm256(const unsigned short* __restrict__ A,   // [M][K] bf16
             const unsigned short* __restrict__ Bt,  // [N][K] bf16
             void* __restrict__ Cp, int N, int K)
{
    extern __shared__ char lds[];   // 131072 B: buf{0,1} x { A[2][128][128B] | B[2][128][128B] }
    const int tid = threadIdx.x;
    const int l   = tid & 63;
    const int l15 = l & 15, lg = l >> 4;
    const int wid = tid >> 6;        // 0..7
    const int wr  = wid >> 2;        // 0..1  (M half)
    const int wc  = wid & 3;         // 0..3  (N strip)

    // XCD-aware bijective swizzle (nwg % 8 == 0 by construction)
    const int nwg = gridDim.x;
    const int bid = blockIdx.x;
    const int wgid = (bid & 7) * (nwg >> 3) + (bid >> 3);
    const int ntx = N >> 8;
    const int bx = wgid % ntx, by = wgid / ntx;
    const int m0 = by * 256, n0 = bx * 256;

    char* const Abase = lds + wr * 16384;                                    // + buf*65536
    char* const Bbase = lds + 32768 + (wc >> 1) * 16384 + (wc & 1) * 8192;   // wave's 64-col strip

    const int l8 = l >> 3, l7 = l & 7;
    const int swslot = (l7 ^ l8) << 3;   // pre-swizzled global column (elems)

    // per-wave staging source rows (this wave stages only what it reads)
    const unsigned short* Ag = A  + (size_t)(m0 + wr * 128 + wc * 16 + l8) * K + swslot;
    const unsigned short* Bg = Bt + (size_t)(n0 + wc * 64 + wr * 16 + l8) * K + swslot;
    char* const Adst = Abase + (wc * 16) * 128 + l * 16;     // + buf*65536 + (r*64)*128
    char* const Bdst = Bbase + (wr * 16) * 128 + l * 16;     // + buf*65536 + (c*32)*128

    f32x4 acc[8][4] = {};
    bf16x8 af[4][2], bf[2][2];

    // prologue: stage tile 0 fully into buf 0, drain, barrier
    stage2(Ag, Adst, K, 0, 0);
    stage2(Bg, Bdst, K, 0, 0);
    stage2(Ag, Adst + 64 * 128, K, 64, 0);
    stage2(Bg, Bdst + 32 * 128, K, 32, 0);
    VMCNT(0);
    BAR();

    const int NT = K >> 6;
    for (int t = 0; t < NT; ++t) {
        const int cb = (t & 1) * 65536, nb = cb ^ 65536;
        const int kn = (t + 1) << 6;
        const bool hn = (t + 1) < NT;
        // P1: quadrant (r0,c0); stage A-q0 of next tile
        lda4(af, Abase + cb, 0, l15, lg);
        ldb2(bf, Bbase + cb, 0, l15, lg);
        if (hn) stage2(Ag, Adst + nb, K, 0, kn);
        BAR();
        mfma16(acc, af, bf, 0, 0);
        VMCNT(4); LGKM0();
        BAR();
        // P2: (r1,c0); stage B-q0
        lda4(af, Abase + cb, 1, l15, lg);
        if (hn) stage2(Bg, Bdst + nb, K, 0, kn);
        BAR();
        mfma16(acc, af, bf, 4, 0);
        VMCNT(4); LGKM0();
        BAR();
        // P3: (r1,c1); stage A-q1
        ldb2(bf, Bbase + cb, 1, l15, lg);
        if (hn) stage2(Ag, Adst + nb + 64 * 128, K, 64, kn);
        BAR();
        mfma16(acc, af, bf, 4, 2);
        LGKM0();
        BAR();
        // P4: (r0,c1); stage B-q1
        lda4(af, Abase + cb, 0, l15, lg);
        if (hn) stage2(Bg, Bdst + nb + 32 * 128, K, 32, kn);
        BAR();
        mfma16(acc, af, bf, 0, 2);
        VMCNT(4); LGKM0();
        BAR();
    }

    // epilogue: C row = (l>>4)*4 + reg, col = l&15
    const int crow = m0 + wr * 128 + lg * 4;
    const int ccol = n0 + wc * 64 + l15;
    #pragma unroll
    for (int mi = 0; mi < 8; ++mi) {
        #pragma unroll
        for (int nj = 0; nj < 4; ++nj) {
            #pragma unroll
            for (int rr = 0; rr < 4; ++rr) {
                int row = crow + mi * 16 + rr;
                int col = ccol + nj * 16;
                float v = acc[mi][nj][rr];
                if (OUT_BF16) ((unsigned short*)Cp)[(size_t)row * N + col] = f2bf(v);
                else          ((float*)Cp)[(size_t)row * N + col] = v;
            }
        }
    }
}

// ---------------- per-head LayerNorm + RoPE, in place on combined QKV bf16 [S][12288] ----------------
__global__ __launch_bounds__(256)
void ln_rope(unsigned short* __restrict__ QKV,
             const float* __restrict__ qg, const float* __restrict__ qb,
             const float* __restrict__ kg, const float* __restrict__ kb,
             const int* __restrict__ pos)
{
    const int tid = threadIdx.x;
    const int l = tid & 63;
    const int w = tid >> 6;
    const int rid = blockIdx.x * 4 + w;
    const int s = rid >> 6;
    const int hh = rid & 63;
    const int which = hh >> 5;
    const int h = hh & 31;
    unsigned short* p = QKV + (size_t)s * QKV_N + which * HID + h * HD;
    const float* gamma = which ? kg : qg;
    const float* beta  = which ? kb : qb;

    float lo = bf2f(p[l]);
    float hi = bf2f(p[l + 64]);
    float sum = lo + hi;
    #pragma unroll
    for (int off = 32; off >= 1; off >>= 1) sum += __shfl_xor(sum, off, 64);
    float mu = sum * (1.0f / 128.0f);
    float dlo = lo - mu, dhi = hi - mu;
    float vs = dlo * dlo + dhi * dhi;
    #pragma unroll
    for (int off = 32; off >= 1; off >>= 1) vs += __shfl_xor(vs, off, 64);
    float rstd = rsqrtf(vs * (1.0f / 128.0f) + 1e-5f);
    float xlo = dlo * rstd * gamma[l] + beta[l];
    float xhi = dhi * rstd * gamma[l + 64] + beta[l + 64];

    float fpos = (float)pos[s];
    float invf = exp2f(-13.287712379549449f * (float)l * (1.0f / 64.0f));
    float ang = fpos * invf;
    float sn, cs;
    sincosf(ang, &sn, &cs);
    p[l]      = f2bf(xlo * cs - xhi * sn);
    p[l + 64] = f2bf(xhi * cs + xlo * sn);
}

// ---------------- causal flash attention, bf16 MFMA ----------------
#define KBLK 32
#define VRS 40

__global__ __launch_bounds__(256)
void attn_fwd(const unsigned short* __restrict__ QKV,   // [S][12288]
              unsigned short* __restrict__ O)           // [S][4096]
{
    __shared__ unsigned short Ks[KBLK * HD];
    __shared__ unsigned short Vt[HD * VRS];
    __shared__ unsigned short Ps[4][16 * VRS];

    const int tid = threadIdx.x;
    const int l = tid & 63;
    const int w = tid >> 6;
    const int l15 = l & 15, lg = l >> 4;
    const int h = blockIdx.y;
    const int q0 = blockIdx.x * 64;
    const int qw = q0 + w * 16;

    const unsigned short* Qp = QKV + h * HD;
    const unsigned short* Kp = QKV + HID + h * HD;
    const unsigned short* Vp = QKV + 2 * HID + h * HD;

    bf16x8 qf[4];
    #pragma unroll
    for (int d = 0; d < 4; ++d)
        qf[d] = *(const bf16x8*)&Qp[(size_t)(qw + l15) * QKV_N + d * 32 + lg * 8];

    f32x4 o_acc[8] = {};
    float mrow[4], lrow[4];
    #pragma unroll
    for (int r = 0; r < 4; ++r) { mrow[r] = -1e30f; lrow[r] = 0.0f; }

    const float scale = 0.08838834764831845f;

    const int nt = (q0 + 64) / KBLK;
    for (int t = 0; t < nt; ++t) {
        const int kv0 = t * KBLK;
        {
            int row = tid >> 3;
            int cbb = (tid & 7) * 32;
            const char* src = (const char*)&Kp[(size_t)(kv0 + row) * QKV_N];
            char* dst = (char*)Ks + row * 256;
            int sw = (row & 7) << 4;
            *(bf16x8*)(dst + ((cbb) ^ sw))      = *(const bf16x8*)(src + cbb);
            *(bf16x8*)(dst + ((cbb + 16) ^ sw)) = *(const bf16x8*)(src + cbb + 16);
        }
        {
            int d = tid & 127;
            int kvb = (tid >> 7) * 4;
            #pragma unroll
            for (int g = 0; g < 4; ++g) {
                int kv = g * 8 + kvb;
                ushort4 o4;
                o4.x = Vp[(size_t)(kv0 + kv + 0) * QKV_N + d];
                o4.y = Vp[(size_t)(kv0 + kv + 1) * QKV_N + d];
                o4.z = Vp[(size_t)(kv0 + kv + 2) * QKV_N + d];
                o4.w = Vp[(size_t)(kv0 + kv + 3) * QKV_N + d];
                *(ushort4*)&Vt[d * VRS + kv] = o4;
            }
        }
        __syncthreads();

        f32x4 sc[2] = {};
        #pragma unroll
        for (int kvf = 0; kvf < 2; ++kvf) {
            int r = kvf * 16 + l15;
            int sw = (r & 7) << 4;
            #pragma unroll
            for (int d = 0; d < 4; ++d) {
                int cbb = (d * 32 + lg * 8) * 2;
                bf16x8 kf = *(const bf16x8*)((const char*)Ks + r * 256 + (cbb ^ sw));
                sc[kvf] = __builtin_amdgcn_mfma_f32_16x16x32_bf16(qf[d], kf, sc[kvf], 0, 0, 0);
            }
        }

        #pragma unroll
        for (int r = 0; r < 4; ++r) {
            int qg = qw + lg * 4 + r;
            float s0 = (kv0 + l15      <= qg) ? sc[0][r] * scale : -1e30f;
            float s1 = (kv0 + 16 + l15 <= qg) ? sc[1][r] * scale : -1e30f;
            float mx = fmaxf(s0, s1);
            #pragma unroll
            for (int off = 8; off >= 1; off >>= 1) mx = fmaxf(mx, __shfl_xor(mx, off, 64));
            float mn = fmaxf(mrow[r], mx);
            float corr = __expf(mrow[r] - mn);
            float p0 = __expf(s0 - mn);
            float p1 = __expf(s1 - mn);
            float rs = p0 + p1;
            #pragma unroll
            for (int off = 8; off >= 1; off >>= 1) rs += __shfl_xor(rs, off, 64);
            lrow[r] = lrow[r] * corr + rs;
            mrow[r] = mn;
            #pragma unroll
            for (int df = 0; df < 8; ++df) o_acc[df][r] *= corr;
            int ql = lg * 4 + r;
            Ps[w][ql * VRS + l15]      = f2bf(p0);
            Ps[w][ql * VRS + 16 + l15] = f2bf(p1);
        }

        bf16x8 pa = *(const bf16x8*)&Ps[w][l15 * VRS + lg * 8];
        #pragma unroll
        for (int df = 0; df < 8; ++df) {
            bf16x8 vf = *(const bf16x8*)&Vt[(df * 16 + l15) * VRS + lg * 8];
            o_acc[df] = __builtin_amdgcn_mfma_f32_16x16x32_bf16(pa, vf, o_acc[df], 0, 0, 0);
        }
        __syncthreads();
    }

    #pragma unroll
    for (int df = 0; df < 8; ++df) {
        #pragma unroll
        for (int r = 0; r < 4; ++r) {
            int q = qw + lg * 4 + r;
            int d = h * HD + df * 16 + l15;
            O[(size_t)q * HID + d] = f2bf(o_acc[df][r] / lrow[r]);
        }
    }
}

extern "C" void kernel_launch(void* const* d_in, const int* in_sizes, int n_in,
                              void* d_out, int out_size, void* d_ws, size_t ws_size,
                              hipStream_t stream)
{
    (void)in_sizes; (void)n_in; (void)out_size; (void)ws_size;
    const float* X    = (const float*)d_in[0];
    const int*   pos  = (const int*)d_in[1];
    const float* Wq   = (const float*)d_in[2];
    const float* Wk   = (const float*)d_in[3];
    const float* Wv   = (const float*)d_in[4];
    const float* Wo   = (const float*)d_in[5];
    const float* qn_w = (const float*)d_in[6];
    const float* qn_b = (const float*)d_in[7];
    const float* kn_w = (const float*)d_in[8];
    const float* kn_b = (const float*)d_in[9];
    float* out = (float*)d_out;

    unsigned short* Xb    = (unsigned short*)d_ws;
    unsigned short* QKVb  = (unsigned short*)((char*)d_ws + 16777216);
    unsigned short* Wt    = (unsigned short*)((char*)d_ws + 67108864);
    unsigned short* Ab    = Xb;

    // allow 128KB dynamic LDS (idempotent; not stream-ordered so safe under capture)
    {
        auto k1 = gemm256<true>;
        auto k2 = gemm256<false>;
        (void)hipFuncSetAttribute((const void*)k1, hipFuncAttributeMaxDynamicSharedMemorySize, 131072);
        (void)hipFuncSetAttribute((const void*)k2, hipFuncAttributeMaxDynamicSharedMemorySize, 131072);
    }

    dim3 blk(256);

    cvt_f32_bf16<<<dim3((S_LEN * HID / 8 + 255) / 256), blk, 0, stream>>>(X, Xb, S_LEN * HID / 8);

    dim3 tgrid(HID / 64, HID / 64);
    cvt_w_t<<<tgrid, blk, 0, stream>>>(Wq, Wt,                         HID, HID);
    cvt_w_t<<<tgrid, blk, 0, stream>>>(Wk, Wt + (size_t)HID * HID,     HID, HID);
    cvt_w_t<<<tgrid, blk, 0, stream>>>(Wv, Wt + (size_t)2 * HID * HID, HID, HID);

    // fused QKV GEMM: [2048,4096] x [12288,4096]^T -> bf16 [2048][12288]
    gemm256<true><<<dim3((S_LEN / 256) * (QKV_N / 256)), dim3(512), 131072, stream>>>(Xb, Wt, QKVb, QKV_N, HID);

    ln_rope<<<dim3(S_LEN * 64 / 4), blk, 0, stream>>>(QKVb, qn_w, qn_b, kn_w, kn_b, pos);

    attn_fwd<<<dim3(S_LEN / 64, NH), blk, 0, stream>>>(QKVb, Ab);

    cvt_w_t<<<tgrid, blk, 0, stream>>>(Wo, Wt, HID, HID);

    // output projection -> fp32
    gemm256<false><<<dim3((S_LEN / 256) * (HID / 256)), dim3(512), 131072, stream>>>(Ab, Wt, out, HID, HID);
}